// Round 3
// baseline (468.157 us; speedup 1.0000x reference)
//
#include <hip/hip_runtime.h>
#include <hip/hip_bf16.h>

typedef __attribute__((ext_vector_type(4))) float f32x4;
typedef __attribute__((ext_vector_type(8))) short bf16x8;

#define NR 12288
#define HD 256
#define TAU 0.5f
#define NT 96                 // 128-row tiles per dim
#define NTRI (NT * (NT + 1) / 2)

__device__ __forceinline__ unsigned short f2bf(float f) {
    unsigned int x = __builtin_bit_cast(unsigned int, f);
    x += 0x7fffu + ((x >> 16) & 1u);
    return (unsigned short)(x >> 16);
}

// ---------- cast f32 -> bf16 (4 elems/thread) ----------
__global__ __launch_bounds__(256) void cast4_kernel(const float* __restrict__ src,
                                                    unsigned short* __restrict__ dst, int n4) {
    int i = blockIdx.x * 256 + threadIdx.x;
    if (i >= n4) return;
    float4 v = ((const float4*)src)[i];
    ushort4 u;
    u.x = f2bf(v.x); u.y = f2bf(v.y); u.z = f2bf(v.z); u.w = f2bf(v.w);
    ((ushort4*)dst)[i] = u;
}

// ---------- W[k][n] f32 -> Wt[n][k] bf16 ----------
__global__ __launch_bounds__(256) void transpose_cast_kernel(const float* __restrict__ W,
                                                             unsigned short* __restrict__ Wt) {
    int n = blockIdx.x;
    int k = threadIdx.x;
    Wt[n * HD + k] = f2bf(W[k * HD + n]);
}

// ---------- projection GEMM: C[M,256] = A[M,256] @ Bt[256,256]^T (+bias, opt elu) ----------
template <int ELU>
__global__ __launch_bounds__(256) void proj_kernel(const unsigned short* __restrict__ A,
                                                   const unsigned short* __restrict__ Bt,
                                                   const float* __restrict__ bias,
                                                   void* __restrict__ Cout) {
    const int lane = threadIdx.x & 63;
    const int wave = threadIdx.x >> 6;
    const int row0 = blockIdx.x * 64;
    const int col0 = wave * 64;
    const int lr = lane & 15, lk = lane >> 4;

    f32x4 acc[4][4] = {};
    const unsigned short* Ab = A + (size_t)(row0 + lr) * HD + lk * 8;
    const unsigned short* Bb = Bt + (size_t)(col0 + lr) * HD + lk * 8;
#pragma unroll
    for (int k0 = 0; k0 < HD; k0 += 32) {
        bf16x8 af[4], bfr[4];
#pragma unroll
        for (int m = 0; m < 4; ++m) af[m] = *(const bf16x8*)(Ab + m * 16 * HD + k0);
#pragma unroll
        for (int n = 0; n < 4; ++n) bfr[n] = *(const bf16x8*)(Bb + n * 16 * HD + k0);
#pragma unroll
        for (int m = 0; m < 4; ++m)
#pragma unroll
            for (int n = 0; n < 4; ++n)
                acc[m][n] = __builtin_amdgcn_mfma_f32_16x16x32_bf16(af[m], bfr[n], acc[m][n], 0, 0, 0);
    }
#pragma unroll
    for (int m = 0; m < 4; ++m) {
#pragma unroll
        for (int n = 0; n < 4; ++n) {
            int col = col0 + n * 16 + lr;
            float b = bias[col];
#pragma unroll
            for (int r = 0; r < 4; ++r) {
                int row = row0 + m * 16 + lk * 4 + r;
                float v = acc[m][n][r] + b;
                if (ELU) {
                    v = v > 0.f ? v : expm1f(v);
                    ((unsigned short*)Cout)[(size_t)row * HD + col] = f2bf(v);
                } else {
                    ((float*)Cout)[(size_t)row * HD + col] = v;
                }
            }
        }
    }
}

// ---------- normalize rows (fp32) -> bf16, plus fp32 diag dot / tau ----------
__global__ __launch_bounds__(256) void norm_diag_kernel(const float* __restrict__ h1,
                                                        const float* __restrict__ h2,
                                                        unsigned short* __restrict__ n1,
                                                        unsigned short* __restrict__ n2,
                                                        float* __restrict__ dvec) {
    const int lane = threadIdx.x & 63;
    const int wave = threadIdx.x >> 6;
    const int row = blockIdx.x * 4 + wave;
    const float4 a = *(const float4*)(h1 + (size_t)row * HD + lane * 4);
    const float4 b = *(const float4*)(h2 + (size_t)row * HD + lane * 4);
    float sa = a.x * a.x + a.y * a.y + a.z * a.z + a.w * a.w;
    float sb = b.x * b.x + b.y * b.y + b.z * b.z + b.w * b.w;
    float sab = a.x * b.x + a.y * b.y + a.z * b.z + a.w * b.w;
#pragma unroll
    for (int m = 32; m; m >>= 1) {
        sa += __shfl_xor(sa, m);
        sb += __shfl_xor(sb, m);
        sab += __shfl_xor(sab, m);
    }
    float na = sqrtf(sa); na = na > 1e-12f ? na : 1e-12f;
    float nb = sqrtf(sb); nb = nb > 1e-12f ? nb : 1e-12f;
    float ia = 1.f / na, ib = 1.f / nb;
    ushort4 u1, u2;
    u1.x = f2bf(a.x * ia); u1.y = f2bf(a.y * ia); u1.z = f2bf(a.z * ia); u1.w = f2bf(a.w * ia);
    u2.x = f2bf(b.x * ib); u2.y = f2bf(b.y * ib); u2.z = f2bf(b.z * ib); u2.w = f2bf(b.w * ib);
    *(ushort4*)(n1 + (size_t)row * HD + lane * 4) = u1;
    *(ushort4*)(n2 + (size_t)row * HD + lane * 4) = u2;
    if (lane == 0) dvec[row] = sab * ia * ib * (1.f / TAU);
}

// ---------- fused similarity: all 3 Gram products, symmetric refl scheduled upper-tri ----------
// LDS layout: [row][slot^ (row&7)] involution swizzle at 16B-slot granularity (T2, rule #21):
//   global_load_lds writes linearly, so the global SOURCE column is pre-swizzled per-lane,
//   and reads apply the same XOR. Conflict-free ds_read_b128 (each 8-lane group covers all
//   8 slots of a 128B row-window exactly once).
__global__ __launch_bounds__(256) void sim_fused_kernel(const unsigned short* __restrict__ n1v,
                                                        const unsigned short* __restrict__ n2v,
                                                        float* __restrict__ R1,
                                                        float* __restrict__ R2,
                                                        float* __restrict__ B1,
                                                        float* __restrict__ B2) {
    __shared__ __align__(16) unsigned short lA[2][128 * 64];  // 2 x 16KB
    __shared__ __align__(16) unsigned short lB[2][128 * 64];  // 2 x 16KB

    const int b = blockIdx.x;
    const unsigned short* X;
    const unsigned short* Y;
    float* rowp;
    float* colp;
    int ti, tj;
    bool diag = false;
    if (b < 2 * NTRI) {
        int p = (b >= NTRI) ? 1 : 0;
        int t = b - p * NTRI;
        int i = (int)((193.f - sqrtf((float)(193 * 193 - 8 * t))) * 0.5f);
        if (i < 0) i = 0;
        if (i > NT - 1) i = NT - 1;
        while (i > 0 && i * NT - i * (i - 1) / 2 > t) --i;
        while ((i + 1) * NT - (i + 1) * i / 2 <= t) ++i;
        int j = i + (t - (i * NT - i * (i - 1) / 2));
        ti = i; tj = j;
        X = p ? n2v : n1v;
        Y = X;
        rowp = p ? R2 : R1;
        diag = (i == j);
        colp = diag ? nullptr : rowp;
    } else {
        int t = b - 2 * NTRI;
        ti = t / NT; tj = t % NT;
        X = n1v; Y = n2v;
        rowp = B1; colp = B2;
    }
    const int r0 = ti * 128, c0 = tj * 128;

    const int t = threadIdx.x;
    const int lane = t & 63, wave = t >> 6;
    const int wr = wave >> 1, wc = wave & 1;
    const int lr = lane & 15, lk = lane >> 4;

    f32x4 acc[4][4] = {};

    // staging: thread t covers 16B; row-in-chunk = lane>>3, source slot pre-swizzled
    const int srow = t >> 3;                                  // 0..31 within 32-row chunk
    const int scol = (((lane & 7) ^ (lane >> 3)) & 7) * 8;    // swizzled 16B slot (ushorts)

    auto STAGE = [&](int kt, int bufi) {
        const int k0 = kt * 64;
#pragma unroll
        for (int c = 0; c < 4; ++c) {
            const unsigned short* ga = X + (size_t)(r0 + c * 32 + srow) * HD + k0 + scol;
            __builtin_amdgcn_global_load_lds(
                (const __attribute__((address_space(1))) unsigned int*)ga,
                (__attribute__((address_space(3))) unsigned int*)(&lA[bufi][(c * 4 + wave) * 512]),
                16, 0, 0);
        }
        if (!diag) {
#pragma unroll
            for (int c = 0; c < 4; ++c) {
                const unsigned short* gb = Y + (size_t)(c0 + c * 32 + srow) * HD + k0 + scol;
                __builtin_amdgcn_global_load_lds(
                    (const __attribute__((address_space(1))) unsigned int*)gb,
                    (__attribute__((address_space(3))) unsigned int*)(&lB[bufi][(c * 4 + wave) * 512]),
                    16, 0, 0);
            }
        }
    };

    const int swz0 = ((lk ^ (lr & 7)) & 7) * 8;        // ks=0 read slot (ushorts)
    const int swz1 = (((4 + lk) ^ (lr & 7)) & 7) * 8;  // ks=1 read slot

    auto COMPUTE = [&](int bufi) {
        const unsigned short* sA = lA[bufi];
        const unsigned short* sB = diag ? lA[bufi] : lB[bufi];
#pragma unroll
        for (int ks = 0; ks < 2; ++ks) {
            const int sw = ks ? swz1 : swz0;
            bf16x8 af[4], bfr[4];
#pragma unroll
            for (int m = 0; m < 4; ++m)
                af[m] = *(const bf16x8*)(sA + (wr * 64 + m * 16 + lr) * 64 + sw);
#pragma unroll
            for (int n = 0; n < 4; ++n)
                bfr[n] = *(const bf16x8*)(sB + (wc * 64 + n * 16 + lr) * 64 + sw);
#pragma unroll
            for (int m = 0; m < 4; ++m)
#pragma unroll
                for (int n = 0; n < 4; ++n)
                    acc[m][n] = __builtin_amdgcn_mfma_f32_16x16x32_bf16(af[m], bfr[n], acc[m][n], 0, 0, 0);
        }
    };

    // 2-phase pipelined K-loop: counted vmcnt, raw barriers (no implicit drain)
    STAGE(0, 0);
#pragma unroll
    for (int kt = 0; kt < 4; ++kt) {
        if (kt + 1 < 4) {
            STAGE(kt + 1, (kt + 1) & 1);
            if (diag) asm volatile("s_waitcnt vmcnt(4)" ::: "memory");
            else      asm volatile("s_waitcnt vmcnt(8)" ::: "memory");
        } else {
            asm volatile("s_waitcnt vmcnt(0)" ::: "memory");
        }
        __builtin_amdgcn_s_barrier();
        COMPUTE(kt & 1);
        asm volatile("s_waitcnt lgkmcnt(0)" ::: "memory");
        __builtin_amdgcn_s_barrier();
    }

    const float kexp = 2.8853901f;  // log2(e)/tau
    float e[4][4][4];
#pragma unroll
    for (int m = 0; m < 4; ++m)
#pragma unroll
        for (int n = 0; n < 4; ++n)
#pragma unroll
            for (int r = 0; r < 4; ++r)
                e[m][n][r] = exp2f(acc[m][n][r] * kexp);

    // rowsum: value (m,n,r): row = r0 + wr*64 + m*16 + lk*4 + r, col = c0 + wc*64 + n*16 + lr
#pragma unroll
    for (int m = 0; m < 4; ++m) {
        float rs[4];
#pragma unroll
        for (int r = 0; r < 4; ++r) {
            rs[r] = e[m][0][r] + e[m][1][r] + e[m][2][r] + e[m][3][r];
            rs[r] += __shfl_xor(rs[r], 1);
            rs[r] += __shfl_xor(rs[r], 2);
            rs[r] += __shfl_xor(rs[r], 4);
            rs[r] += __shfl_xor(rs[r], 8);
        }
        if (lr == 0) {
#pragma unroll
            for (int r = 0; r < 4; ++r)
                atomicAdd(&rowp[r0 + wr * 64 + m * 16 + lk * 4 + r], rs[r]);
        }
    }
    if (colp) {
#pragma unroll
        for (int n = 0; n < 4; ++n) {
            float cs = 0.f;
#pragma unroll
            for (int m = 0; m < 4; ++m)
#pragma unroll
                for (int r = 0; r < 4; ++r) cs += e[m][n][r];
            cs += __shfl_xor(cs, 16);
            cs += __shfl_xor(cs, 32);
            if (lk == 0) atomicAdd(&colp[c0 + wc * 64 + n * 16 + lr], cs);
        }
    }
}

// ---------- loss ----------
__global__ __launch_bounds__(128) void loss_partial_kernel(const float* __restrict__ R1,
                                                           const float* __restrict__ B1,
                                                           const float* __restrict__ R2,
                                                           const float* __restrict__ B2,
                                                           const float* __restrict__ dvec,
                                                           float* __restrict__ partial) {
    int i = blockIdx.x * 128 + threadIdx.x;
    const float e2 = 7.389056099f;  // exp(1/tau)
    float d = dvec[i];
    float l1 = logf(R1[i] + B1[i] - e2) - d;
    float l2 = logf(R2[i] + B2[i] - e2) - d;
    float v = 0.5f * (l1 + l2);
#pragma unroll
    for (int m = 32; m; m >>= 1) v += __shfl_xor(v, m);
    __shared__ float wsum[2];
    if ((threadIdx.x & 63) == 0) wsum[threadIdx.x >> 6] = v;
    __syncthreads();
    if (threadIdx.x == 0) partial[blockIdx.x] = wsum[0] + wsum[1];
}

__global__ __launch_bounds__(128) void loss_final_kernel(const float* __restrict__ partial,
                                                         float* __restrict__ out, int nb) {
    float s = 0.f;
    for (int i = threadIdx.x; i < nb; i += 128) s += partial[i];
#pragma unroll
    for (int m = 32; m; m >>= 1) s += __shfl_xor(s, m);
    __shared__ float wsum[2];
    if ((threadIdx.x & 63) == 0) wsum[threadIdx.x >> 6] = s;
    __syncthreads();
    if (threadIdx.x == 0) out[0] = (wsum[0] + wsum[1]) * (1.f / (float)NR);
}

extern "C" void kernel_launch(void* const* d_in, const int* in_sizes, int n_in,
                              void* d_out, int out_size, void* d_ws, size_t ws_size,
                              hipStream_t stream) {
    const float* z1 = (const float*)d_in[0];
    const float* z2 = (const float*)d_in[1];
    const float* W1 = (const float*)d_in[2];
    const float* b1 = (const float*)d_in[3];
    const float* W2 = (const float*)d_in[4];
    const float* b2 = (const float*)d_in[5];

    char* ws = (char*)d_ws;
    size_t off = 0;
    auto alloc = [&](size_t bytes) {
        void* p = ws + off;
        off += (bytes + 255) & ~(size_t)255;
        return p;
    };
    const size_t NH2 = (size_t)NR * HD * 2;  // bf16 matrix bytes
    unsigned short* zb1 = (unsigned short*)alloc(NH2);
    unsigned short* zb2 = (unsigned short*)alloc(NH2);
    unsigned short* W1t = (unsigned short*)alloc(HD * HD * 2);
    unsigned short* W2t = (unsigned short*)alloc(HD * HD * 2);
    unsigned short* t1 = (unsigned short*)alloc(NH2);
    unsigned short* t2 = (unsigned short*)alloc(NH2);
    float* h1 = (float*)alloc((size_t)NR * HD * 4);
    float* h2 = (float*)alloc((size_t)NR * HD * 4);
    unsigned short* n1 = (unsigned short*)alloc(NH2);
    unsigned short* n2 = (unsigned short*)alloc(NH2);
    float* R1 = (float*)alloc(NR * 4);
    float* B1 = (float*)alloc(NR * 4);
    float* B2 = (float*)alloc(NR * 4);
    float* R2 = (float*)alloc(NR * 4);
    float* dvec = (float*)alloc(NR * 4);
    float* partial = (float*)alloc(96 * 4);

    const int n4 = NR * HD / 4;
    cast4_kernel<<<(n4 + 255) / 256, 256, 0, stream>>>(z1, zb1, n4);
    cast4_kernel<<<(n4 + 255) / 256, 256, 0, stream>>>(z2, zb2, n4);
    transpose_cast_kernel<<<HD, 256, 0, stream>>>(W1, W1t);
    transpose_cast_kernel<<<HD, 256, 0, stream>>>(W2, W2t);

    proj_kernel<1><<<NR / 64, 256, 0, stream>>>(zb1, W1t, b1, t1);
    proj_kernel<1><<<NR / 64, 256, 0, stream>>>(zb2, W1t, b1, t2);
    proj_kernel<0><<<NR / 64, 256, 0, stream>>>(t1, W2t, b2, h1);
    proj_kernel<0><<<NR / 64, 256, 0, stream>>>(t2, W2t, b2, h2);

    norm_diag_kernel<<<NR / 4, 256, 0, stream>>>(h1, h2, n1, n2, dvec);

    hipMemsetAsync(R1, 0, (size_t)NR * 4 * 4, stream);  // R1,B1,B2,R2 contiguous

    sim_fused_kernel<<<2 * NTRI + NT * NT, 256, 0, stream>>>(n1, n2, R1, R2, B1, B2);

    loss_partial_kernel<<<NR / 128, 128, 0, stream>>>(R1, B1, R2, B2, dvec, partial);
    loss_final_kernel<<<1, 128, 0, stream>>>(partial, (float*)d_out, NR / 128);
}

// Round 4
// 353.364 us; speedup vs baseline: 1.3249x; 1.3249x over previous
//
#include <hip/hip_runtime.h>
#include <hip/hip_bf16.h>

typedef __attribute__((ext_vector_type(4))) float f32x4;
typedef __attribute__((ext_vector_type(8))) short bf16x8;

#define NR 12288
#define HD 256
#define TAU 0.5f
#define NU 24576              // unified rows (n1;n2)
#define NP 96                 // 256-row panels of unified matrix
#define NSUB 384              // partial-sum slots

__device__ __forceinline__ unsigned short f2bf(float f) {
    unsigned int x = __builtin_bit_cast(unsigned int, f);
    x += 0x7fffu + ((x >> 16) & 1u);
    return (unsigned short)(x >> 16);
}

// ---------- cast f32 -> bf16 (4 elems/thread) ----------
__global__ __launch_bounds__(256) void cast4_kernel(const float* __restrict__ src,
                                                    unsigned short* __restrict__ dst, int n4) {
    int i = blockIdx.x * 256 + threadIdx.x;
    if (i >= n4) return;
    float4 v = ((const float4*)src)[i];
    ushort4 u;
    u.x = f2bf(v.x); u.y = f2bf(v.y); u.z = f2bf(v.z); u.w = f2bf(v.w);
    ((ushort4*)dst)[i] = u;
}

// ---------- W[k][n] f32 -> Wt[n][k] bf16 ----------
__global__ __launch_bounds__(256) void transpose_cast_kernel(const float* __restrict__ W,
                                                             unsigned short* __restrict__ Wt) {
    int n = blockIdx.x;
    int k = threadIdx.x;
    Wt[n * HD + k] = f2bf(W[k * HD + n]);
}

// ---------- projection GEMM: C[M,256] = A[M,256] @ Bt[256,256]^T (+bias, opt elu) ----------
template <int ELU>
__global__ __launch_bounds__(256) void proj_kernel(const unsigned short* __restrict__ A,
                                                   const unsigned short* __restrict__ Bt,
                                                   const float* __restrict__ bias,
                                                   void* __restrict__ Cout) {
    const int lane = threadIdx.x & 63;
    const int wave = threadIdx.x >> 6;
    const int row0 = blockIdx.x * 64;
    const int col0 = wave * 64;
    const int lr = lane & 15, lk = lane >> 4;

    f32x4 acc[4][4] = {};
    const unsigned short* Ab = A + (size_t)(row0 + lr) * HD + lk * 8;
    const unsigned short* Bb = Bt + (size_t)(col0 + lr) * HD + lk * 8;
#pragma unroll
    for (int k0 = 0; k0 < HD; k0 += 32) {
        bf16x8 af[4], bfr[4];
#pragma unroll
        for (int m = 0; m < 4; ++m) af[m] = *(const bf16x8*)(Ab + m * 16 * HD + k0);
#pragma unroll
        for (int n = 0; n < 4; ++n) bfr[n] = *(const bf16x8*)(Bb + n * 16 * HD + k0);
#pragma unroll
        for (int m = 0; m < 4; ++m)
#pragma unroll
            for (int n = 0; n < 4; ++n)
                acc[m][n] = __builtin_amdgcn_mfma_f32_16x16x32_bf16(af[m], bfr[n], acc[m][n], 0, 0, 0);
    }
#pragma unroll
    for (int m = 0; m < 4; ++m) {
#pragma unroll
        for (int n = 0; n < 4; ++n) {
            int col = col0 + n * 16 + lr;
            float b = bias[col];
#pragma unroll
            for (int r = 0; r < 4; ++r) {
                int row = row0 + m * 16 + lk * 4 + r;
                float v = acc[m][n][r] + b;
                if (ELU) {
                    v = v > 0.f ? v : expm1f(v);
                    ((unsigned short*)Cout)[(size_t)row * HD + col] = f2bf(v);
                } else {
                    ((float*)Cout)[(size_t)row * HD + col] = v;
                }
            }
        }
    }
}

// ---------- normalize rows (fp32) -> bf16 into unified buffer, plus fp32 diag dot / tau ----------
__global__ __launch_bounds__(256) void norm_diag_kernel(const float* __restrict__ h1,
                                                        const float* __restrict__ h2,
                                                        unsigned short* __restrict__ n1,
                                                        unsigned short* __restrict__ n2,
                                                        float* __restrict__ dvec) {
    const int lane = threadIdx.x & 63;
    const int wave = threadIdx.x >> 6;
    const int row = blockIdx.x * 4 + wave;
    const float4 a = *(const float4*)(h1 + (size_t)row * HD + lane * 4);
    const float4 b = *(const float4*)(h2 + (size_t)row * HD + lane * 4);
    float sa = a.x * a.x + a.y * a.y + a.z * a.z + a.w * a.w;
    float sb = b.x * b.x + b.y * b.y + b.z * b.z + b.w * b.w;
    float sab = a.x * b.x + a.y * b.y + a.z * b.z + a.w * b.w;
#pragma unroll
    for (int m = 32; m; m >>= 1) {
        sa += __shfl_xor(sa, m);
        sb += __shfl_xor(sb, m);
        sab += __shfl_xor(sab, m);
    }
    float na = sqrtf(sa); na = na > 1e-12f ? na : 1e-12f;
    float nb = sqrtf(sb); nb = nb > 1e-12f ? nb : 1e-12f;
    float ia = 1.f / na, ib = 1.f / nb;
    ushort4 u1, u2;
    u1.x = f2bf(a.x * ia); u1.y = f2bf(a.y * ia); u1.z = f2bf(a.z * ia); u1.w = f2bf(a.w * ia);
    u2.x = f2bf(b.x * ib); u2.y = f2bf(b.y * ib); u2.z = f2bf(b.z * ib); u2.w = f2bf(b.w * ib);
    *(ushort4*)(n1 + (size_t)row * HD + lane * 4) = u1;
    *(ushort4*)(n2 + (size_t)row * HD + lane * 4) = u2;
    if (lane == 0) dvec[row] = sab * ia * ib * (1.f / TAU);
}

// ---------- unified symmetric Gram: upper-tri 256x256 tiles of exp(M@M^T/tau) ----------
// Block (i,j), i<=j: computes tile, writes rowsum partials (over its 256 cols) to
// RPART[4j+wc][rows of panel i], and (off-diag) colsum partials to RPART[2i+wr][rows of panel j].
// Slot disjointness: panel-p rows receive rowsum subs {4j+wc : j>=p} = [4p,384) and
// colsum subs {2h+wr : h<p} = [0,2p) — disjoint; unused slots stay zero (memset).
__global__ __launch_bounds__(512, 2) void gram_kernel(const unsigned short* __restrict__ nUv,
                                                      float* __restrict__ RPART) {
    __shared__ __align__(16) unsigned short lA[2][256 * 64];  // 2 x 32KB
    __shared__ __align__(16) unsigned short lB[2][256 * 64];  // 2 x 32KB

    // tri decode (i<=j) over NP=96
    const int t0 = blockIdx.x;
    int i = (int)((193.f - sqrtf((float)(193 * 193 - 8 * t0))) * 0.5f);
    if (i < 0) i = 0;
    if (i > NP - 1) i = NP - 1;
    while (i > 0 && i * NP - i * (i - 1) / 2 > t0) --i;
    while ((i + 1) * NP - (i + 1) * i / 2 <= t0) ++i;
    const int j = i + (t0 - (i * NP - i * (i - 1) / 2));
    const bool diag = (i == j);

    const unsigned short* X = nUv + (size_t)i * 256 * HD;
    const unsigned short* Y = nUv + (size_t)j * 256 * HD;

    const int t = threadIdx.x;
    const int lane = t & 63;
    const int wave = t >> 6;
    const int wr = wave >> 2, wc = wave & 3;      // 2M x 4N wave grid; wave tile 128x64
    const int lr = lane & 15, lk = lane >> 4;

    f32x4 acc[8][4] = {};

    // staging: thread t covers 16B; chunk c = 64 rows; source slot pre-swizzled (T2, rule #21)
    const int srow = t >> 3;                         // 0..63 row within chunk
    const int scol = ((t & 7) ^ (srow & 7)) * 8;     // swizzled 16B slot (ushort units)

    auto STAGE = [&](int kt, int bufi) {
        const int k0 = kt * 64;
#pragma unroll
        for (int c = 0; c < 4; ++c) {
            const unsigned short* ga = X + (size_t)(c * 64 + srow) * HD + k0 + scol;
            __builtin_amdgcn_global_load_lds(
                (const __attribute__((address_space(1))) unsigned int*)ga,
                (__attribute__((address_space(3))) unsigned int*)(&lA[bufi][c * 4096 + t * 8]),
                16, 0, 0);
        }
        if (!diag) {
#pragma unroll
            for (int c = 0; c < 4; ++c) {
                const unsigned short* gb = Y + (size_t)(c * 64 + srow) * HD + k0 + scol;
                __builtin_amdgcn_global_load_lds(
                    (const __attribute__((address_space(1))) unsigned int*)gb,
                    (__attribute__((address_space(3))) unsigned int*)(&lB[bufi][c * 4096 + t * 8]),
                    16, 0, 0);
            }
        }
    };

    auto COMPUTE = [&](int bufi) {
        const unsigned short* sA = lA[bufi];
        const unsigned short* sB = diag ? lA[bufi] : lB[bufi];
#pragma unroll
        for (int ks = 0; ks < 2; ++ks) {
            const int pos = ((ks * 4 + lk) ^ (lr & 7)) * 8;   // swizzled read slot
            bf16x8 af[8], bfr[4];
#pragma unroll
            for (int m = 0; m < 8; ++m)
                af[m] = *(const bf16x8*)(sA + (wr * 128 + m * 16 + lr) * 64 + pos);
#pragma unroll
            for (int n = 0; n < 4; ++n)
                bfr[n] = *(const bf16x8*)(sB + (wc * 64 + n * 16 + lr) * 64 + pos);
#pragma unroll
            for (int m = 0; m < 8; ++m)
#pragma unroll
                for (int n = 0; n < 4; ++n)
                    acc[m][n] = __builtin_amdgcn_mfma_f32_16x16x32_bf16(af[m], bfr[n], acc[m][n], 0, 0, 0);
        }
    };

    // 2-phase pipelined K-loop: counted vmcnt, raw barriers
    STAGE(0, 0);
#pragma unroll
    for (int kt = 0; kt < 4; ++kt) {
        if (kt < 3) {
            STAGE(kt + 1, (kt + 1) & 1);
            if (diag) asm volatile("s_waitcnt vmcnt(4)" ::: "memory");
            else      asm volatile("s_waitcnt vmcnt(8)" ::: "memory");
        } else {
            asm volatile("s_waitcnt vmcnt(0)" ::: "memory");
        }
        __builtin_amdgcn_s_barrier();
        COMPUTE(kt & 1);
        asm volatile("s_waitcnt lgkmcnt(0)" ::: "memory");
        __builtin_amdgcn_s_barrier();
    }

    const float kexp = 2.8853901f;  // log2(e)/tau
#pragma unroll
    for (int m = 0; m < 8; ++m)
#pragma unroll
        for (int n = 0; n < 4; ++n)
#pragma unroll
            for (int r = 0; r < 4; ++r)
                acc[m][n][r] = exp2f(acc[m][n][r] * kexp);

    // rowsum partials: value (m,n,r): row = i*256 + wr*128 + m*16 + lk*4 + r (sum over wave's 64 cols)
    {
        float* dst = RPART + (size_t)(4 * j + wc) * NU + i * 256 + wr * 128;
#pragma unroll
        for (int m = 0; m < 8; ++m) {
            float rs[4];
#pragma unroll
            for (int r = 0; r < 4; ++r) {
                rs[r] = acc[m][0][r] + acc[m][1][r] + acc[m][2][r] + acc[m][3][r];
                rs[r] += __shfl_xor(rs[r], 1);
                rs[r] += __shfl_xor(rs[r], 2);
                rs[r] += __shfl_xor(rs[r], 4);
                rs[r] += __shfl_xor(rs[r], 8);
            }
            if (lr == 0) {
#pragma unroll
                for (int r = 0; r < 4; ++r) dst[m * 16 + lk * 4 + r] = rs[r];
            }
        }
    }
    // colsum partials (off-diag): col = j*256 + wc*64 + n*16 + lr (sum over wave's 128 rows)
    if (!diag) {
        float* dst = RPART + (size_t)(2 * i + wr) * NU + j * 256 + wc * 64;
#pragma unroll
        for (int n = 0; n < 4; ++n) {
            float cs = 0.f;
#pragma unroll
            for (int m = 0; m < 8; ++m)
#pragma unroll
                for (int r = 0; r < 4; ++r) cs += acc[m][n][r];
            cs += __shfl_xor(cs, 16);
            cs += __shfl_xor(cs, 32);
            if (lk == 0) dst[n * 16 + lr] = cs;
        }
    }
}

// ---------- reduce partials: S[r] = sum_s RPART[s][r] ----------
__global__ __launch_bounds__(256) void reduce_part_kernel(const float* __restrict__ RPART,
                                                          float* __restrict__ S) {
    const int r = blockIdx.x * 256 + threadIdx.x;
    float s = 0.f;
#pragma unroll 8
    for (int p = 0; p < NSUB; ++p) s += RPART[(size_t)p * NU + r];
    S[r] = s;
}

// ---------- loss ----------
__global__ __launch_bounds__(128) void loss_partial_kernel(const float* __restrict__ S,
                                                           const float* __restrict__ dvec,
                                                           float* __restrict__ partial) {
    int i = blockIdx.x * 128 + threadIdx.x;
    const float e2 = 7.389056099f;  // exp(1/tau)
    float d = dvec[i];
    float l1 = logf(S[i] - e2) - d;
    float l2 = logf(S[NR + i] - e2) - d;
    float v = 0.5f * (l1 + l2);
#pragma unroll
    for (int m = 32; m; m >>= 1) v += __shfl_xor(v, m);
    __shared__ float wsum[2];
    if ((threadIdx.x & 63) == 0) wsum[threadIdx.x >> 6] = v;
    __syncthreads();
    if (threadIdx.x == 0) partial[blockIdx.x] = wsum[0] + wsum[1];
}

__global__ __launch_bounds__(128) void loss_final_kernel(const float* __restrict__ partial,
                                                         float* __restrict__ out, int nb) {
    float s = 0.f;
    for (int i = threadIdx.x; i < nb; i += 128) s += partial[i];
#pragma unroll
    for (int m = 32; m; m >>= 1) s += __shfl_xor(s, m);
    __shared__ float wsum[2];
    if ((threadIdx.x & 63) == 0) wsum[threadIdx.x >> 6] = s;
    __syncthreads();
    if (threadIdx.x == 0) out[0] = (wsum[0] + wsum[1]) * (1.f / (float)NR);
}

extern "C" void kernel_launch(void* const* d_in, const int* in_sizes, int n_in,
                              void* d_out, int out_size, void* d_ws, size_t ws_size,
                              hipStream_t stream) {
    const float* z1 = (const float*)d_in[0];
    const float* z2 = (const float*)d_in[1];
    const float* W1 = (const float*)d_in[2];
    const float* b1 = (const float*)d_in[3];
    const float* W2 = (const float*)d_in[4];
    const float* b2 = (const float*)d_in[5];

    char* ws = (char*)d_ws;
    size_t off = 0;
    auto alloc = [&](size_t bytes) {
        void* p = ws + off;
        off += (bytes + 255) & ~(size_t)255;
        return p;
    };
    const size_t NH2 = (size_t)NR * HD * 2;  // bf16 matrix bytes (6.29 MB)
    unsigned short* zb1 = (unsigned short*)alloc(NH2);
    unsigned short* zb2 = (unsigned short*)alloc(NH2);
    unsigned short* W1t = (unsigned short*)alloc(HD * HD * 2);
    unsigned short* W2t = (unsigned short*)alloc(HD * HD * 2);
    unsigned short* t1 = (unsigned short*)alloc(NH2);
    unsigned short* t2 = (unsigned short*)alloc(NH2);
    float* h1 = (float*)alloc((size_t)NR * HD * 4);
    float* h2 = (float*)alloc((size_t)NR * HD * 4);
    unsigned short* nU = (unsigned short*)alloc((size_t)NU * HD * 2);
    float* S = (float*)alloc((size_t)NU * 4);
    float* dvec = (float*)alloc(NR * 4);
    float* partial = (float*)alloc(96 * 4);
    // RPART aliases the dead zb/W/t chain + most of h1 (all consumed before memset below).
    float* RPART = (float*)ws;  // 384*24576*4 = 37,748,736 B < h2 offset (38,010,880)

    const int n4 = NR * HD / 4;
    cast4_kernel<<<(n4 + 255) / 256, 256, 0, stream>>>(z1, zb1, n4);
    cast4_kernel<<<(n4 + 255) / 256, 256, 0, stream>>>(z2, zb2, n4);
    transpose_cast_kernel<<<HD, 256, 0, stream>>>(W1, W1t);
    transpose_cast_kernel<<<HD, 256, 0, stream>>>(W2, W2t);

    proj_kernel<1><<<NR / 64, 256, 0, stream>>>(zb1, W1t, b1, t1);
    proj_kernel<1><<<NR / 64, 256, 0, stream>>>(zb2, W1t, b1, t2);
    proj_kernel<0><<<NR / 64, 256, 0, stream>>>(t1, W2t, b2, h1);
    proj_kernel<0><<<NR / 64, 256, 0, stream>>>(t2, W2t, b2, h2);

    norm_diag_kernel<<<NR / 4, 256, 0, stream>>>(h1, h2, nU, nU + (size_t)NR * HD, dvec);

    hipMemsetAsync(RPART, 0, (size_t)NSUB * NU * 4, stream);

    gram_kernel<<<NP * (NP + 1) / 2, 512, 0, stream>>>(nU, RPART);

    reduce_part_kernel<<<NU / 256, 256, 0, stream>>>(RPART, S);

    loss_partial_kernel<<<NR / 128, 128, 0, stream>>>(S, dvec, partial);
    loss_final_kernel<<<1, 128, 0, stream>>>(partial, (float*)d_out, NR / 128);
}

// Round 5
// 330.720 us; speedup vs baseline: 1.4156x; 1.0685x over previous
//
#include <hip/hip_runtime.h>
#include <hip/hip_bf16.h>

typedef __attribute__((ext_vector_type(4))) float f32x4;
typedef __attribute__((ext_vector_type(8))) short bf16x8;

#define NR 12288
#define HD 256
#define TAU 0.5f
#define NU 24576              // unified rows (n1;n2)
#define NP 96                 // 256-row panels of unified matrix
#define NSUB 384              // partial-sum slots
#define NBLK (NP * (NP + 1) / 2)   // 4656 = 8 * 582

__device__ __forceinline__ unsigned short f2bf(float f) {
    unsigned int x = __builtin_bit_cast(unsigned int, f);
    x += 0x7fffu + ((x >> 16) & 1u);
    return (unsigned short)(x >> 16);
}

// manual OCP e4m3fn cast, RNE in normal range, step-round in denormal range
__device__ __forceinline__ unsigned char f2e4m3(float f) {
    unsigned int u = __builtin_bit_cast(unsigned int, f);
    unsigned int s = (u >> 24) & 0x80u;
    float af = fabsf(f);
    if (af >= 464.f) return (unsigned char)(s | 0x7Eu);      // saturate to 448
    if (af < 0.015625f) {                                    // denormal: step 2^-9 (q=8 -> 0x08 = 2^-6, correct)
        unsigned int q = (unsigned int)(af * 512.f + 0.5f);
        return (unsigned char)(s | q);
    }
    int e = (int)((u >> 23) & 0xffu) - 127;
    unsigned int mant = u & 0x7fffffu;
    unsigned int val = (unsigned int)((e + 7) << 3) | (mant >> 20);
    unsigned int rem = mant & 0xfffffu;
    val += (rem > 0x80000u) || (rem == 0x80000u && (val & 1u));
    return (unsigned char)(s | val);
}

// ---------- cast f32 -> bf16 (4 elems/thread) ----------
__global__ __launch_bounds__(256) void cast4_kernel(const float* __restrict__ src,
                                                    unsigned short* __restrict__ dst, int n4) {
    int i = blockIdx.x * 256 + threadIdx.x;
    if (i >= n4) return;
    float4 v = ((const float4*)src)[i];
    ushort4 u;
    u.x = f2bf(v.x); u.y = f2bf(v.y); u.z = f2bf(v.z); u.w = f2bf(v.w);
    ((ushort4*)dst)[i] = u;
}

// ---------- W[k][n] f32 -> Wt[n][k] bf16 ----------
__global__ __launch_bounds__(256) void transpose_cast_kernel(const float* __restrict__ W,
                                                             unsigned short* __restrict__ Wt) {
    int n = blockIdx.x;
    int k = threadIdx.x;
    Wt[n * HD + k] = f2bf(W[k * HD + n]);
}

// ---------- projection GEMM: C[M,256] = A[M,256] @ Bt[256,256]^T (+bias, opt elu) ----------
template <int ELU>
__global__ __launch_bounds__(256) void proj_kernel(const unsigned short* __restrict__ A,
                                                   const unsigned short* __restrict__ Bt,
                                                   const float* __restrict__ bias,
                                                   void* __restrict__ Cout) {
    const int lane = threadIdx.x & 63;
    const int wave = threadIdx.x >> 6;
    const int row0 = blockIdx.x * 64;
    const int col0 = wave * 64;
    const int lr = lane & 15, lk = lane >> 4;

    f32x4 acc[4][4] = {};
    const unsigned short* Ab = A + (size_t)(row0 + lr) * HD + lk * 8;
    const unsigned short* Bb = Bt + (size_t)(col0 + lr) * HD + lk * 8;
#pragma unroll
    for (int k0 = 0; k0 < HD; k0 += 32) {
        bf16x8 af[4], bfr[4];
#pragma unroll
        for (int m = 0; m < 4; ++m) af[m] = *(const bf16x8*)(Ab + m * 16 * HD + k0);
#pragma unroll
        for (int n = 0; n < 4; ++n) bfr[n] = *(const bf16x8*)(Bb + n * 16 * HD + k0);
#pragma unroll
        for (int m = 0; m < 4; ++m)
#pragma unroll
            for (int n = 0; n < 4; ++n)
                acc[m][n] = __builtin_amdgcn_mfma_f32_16x16x32_bf16(af[m], bfr[n], acc[m][n], 0, 0, 0);
    }
#pragma unroll
    for (int m = 0; m < 4; ++m) {
#pragma unroll
        for (int n = 0; n < 4; ++n) {
            int col = col0 + n * 16 + lr;
            float b = bias[col];
#pragma unroll
            for (int r = 0; r < 4; ++r) {
                int row = row0 + m * 16 + lk * 4 + r;
                float v = acc[m][n][r] + b;
                if (ELU) {
                    v = v > 0.f ? v : expm1f(v);
                    ((unsigned short*)Cout)[(size_t)row * HD + col] = f2bf(v);
                } else {
                    ((float*)Cout)[(size_t)row * HD + col] = v;
                }
            }
        }
    }
}

// ---------- normalize rows (fp32) -> fp8 e4m3 into unified buffer, plus fp32 diag dot / tau ----------
__global__ __launch_bounds__(256) void norm_diag_kernel(const float* __restrict__ h1,
                                                        const float* __restrict__ h2,
                                                        unsigned char* __restrict__ n1,
                                                        unsigned char* __restrict__ n2,
                                                        float* __restrict__ dvec) {
    const int lane = threadIdx.x & 63;
    const int wave = threadIdx.x >> 6;
    const int row = blockIdx.x * 4 + wave;
    const float4 a = *(const float4*)(h1 + (size_t)row * HD + lane * 4);
    const float4 b = *(const float4*)(h2 + (size_t)row * HD + lane * 4);
    float sa = a.x * a.x + a.y * a.y + a.z * a.z + a.w * a.w;
    float sb = b.x * b.x + b.y * b.y + b.z * b.z + b.w * b.w;
    float sab = a.x * b.x + a.y * b.y + a.z * b.z + a.w * b.w;
#pragma unroll
    for (int m = 32; m; m >>= 1) {
        sa += __shfl_xor(sa, m);
        sb += __shfl_xor(sb, m);
        sab += __shfl_xor(sab, m);
    }
    float na = sqrtf(sa); na = na > 1e-12f ? na : 1e-12f;
    float nb = sqrtf(sb); nb = nb > 1e-12f ? nb : 1e-12f;
    float ia = 1.f / na, ib = 1.f / nb;
    uchar4 q1, q2;
    q1.x = f2e4m3(a.x * ia); q1.y = f2e4m3(a.y * ia); q1.z = f2e4m3(a.z * ia); q1.w = f2e4m3(a.w * ia);
    q2.x = f2e4m3(b.x * ib); q2.y = f2e4m3(b.y * ib); q2.z = f2e4m3(b.z * ib); q2.w = f2e4m3(b.w * ib);
    *(uchar4*)(n1 + (size_t)row * HD + lane * 4) = q1;
    *(uchar4*)(n2 + (size_t)row * HD + lane * 4) = q2;
    if (lane == 0) dvec[row] = sab * ia * ib * (1.f / TAU);
}

// ---------- unified symmetric Gram (fp8): upper-tri 256x256 tiles of exp(M@M^T/tau) ----------
// Both full K=256 panels resident in LDS (64 KiB each): ONE staging burst + ONE barrier,
// then a barrier-free MFMA loop. 16B-chunk XOR swizzle (chunk ^= row&15), both sides
// (pre-swizzled global source for global_load_lds + swizzled ds_read addr) per rule #21.
// Partial-sum slots: rowsum -> RPART[4j+wc], colsum (i<j) -> RPART[2i+wr]; disjoint by panel.
__global__ __launch_bounds__(512, 2) void gram_kernel(const unsigned char* __restrict__ nU8,
                                                      float* __restrict__ RPART) {
    __shared__ __align__(16) unsigned char lA[256 * 256];  // 64KB
    __shared__ __align__(16) unsigned char lB[256 * 256];  // 64KB

    // XCD-aware swizzle (bijective: 4656 = 8*582), then tri decode (i<=j) over NP=96
    const int bid = blockIdx.x;
    const int t0 = (bid & 7) * (NBLK / 8) + (bid >> 3);
    int i = (int)((193.f - sqrtf((float)(193 * 193 - 8 * t0))) * 0.5f);
    if (i < 0) i = 0;
    if (i > NP - 1) i = NP - 1;
    while (i > 0 && i * NP - i * (i - 1) / 2 > t0) --i;
    while ((i + 1) * NP - (i + 1) * i / 2 <= t0) ++i;
    const int j = i + (t0 - (i * NP - i * (i - 1) / 2));
    const bool diag = (i == j);

    const unsigned char* X = nU8 + (size_t)i * 256 * HD;
    const unsigned char* Y = nU8 + (size_t)j * 256 * HD;

    const int t = threadIdx.x;
    const int lane = t & 63;
    const int wave = t >> 6;
    const int wr = wave >> 2, wc = wave & 3;      // 2M x 4N wave grid; wave tile 128x64
    const int lr = lane & 15, lk = lane >> 4;

    // ---- stage both panels: per thread 8 chunks of 16B per operand ----
    // LDS linear pos p = c*8192 + t*16 -> (row = c*32 + t/16, slot = t&15);
    // source chunk = slot ^ (row&15); row&15 = (t>>4)&15 (c*32 = 0 mod 16... 32*c keeps low 4 bits of row = (t>>4)&15? row = c*32 + (t>>4); 32c mod 16 = 0 ✓)
    {
        const int rbase = t >> 4;                              // 0..31
        const int schunk = (t & 15) ^ (rbase & 15);            // pre-swizzled source slot
        const unsigned char* gx = X + rbase * 256 + schunk * 16;
        const unsigned char* gy = Y + rbase * 256 + schunk * 16;
#pragma unroll
        for (int c = 0; c < 8; ++c) {
            __builtin_amdgcn_global_load_lds(
                (const __attribute__((address_space(1))) unsigned int*)(gx + c * 8192),
                (__attribute__((address_space(3))) unsigned int*)(&lA[c * 8192 + t * 16]),
                16, 0, 0);
        }
#pragma unroll
        for (int c = 0; c < 8; ++c) {
            __builtin_amdgcn_global_load_lds(
                (const __attribute__((address_space(1))) unsigned int*)(gy + c * 8192),
                (__attribute__((address_space(3))) unsigned int*)(&lB[c * 8192 + t * 16]),
                16, 0, 0);
        }
    }
    __syncthreads();   // vmcnt(0) + barrier; the ONLY barrier in this kernel

    // ---- barrier-free K-loop: 8 k-steps of K=32, fp8 MFMA ----
    f32x4 acc[8][4] = {};
    const unsigned char* sA = lA + (size_t)(wr * 128 + lr) * 256 + (lk & 1) * 8;
    const unsigned char* sB = lB + (size_t)(wc * 64 + lr) * 256 + (lk & 1) * 8;
#pragma unroll
    for (int ks = 0; ks < 8; ++ks) {
        const int chnk = ((2 * ks + (lk >> 1)) ^ lr) * 16;     // swizzled 16B chunk
        long af[8], bfr[4];
#pragma unroll
        for (int m = 0; m < 8; ++m)
            af[m] = *(const long*)(sA + m * 16 * 256 + chnk);
#pragma unroll
        for (int n = 0; n < 4; ++n)
            bfr[n] = *(const long*)(sB + n * 16 * 256 + chnk);
#pragma unroll
        for (int m = 0; m < 8; ++m)
#pragma unroll
            for (int n = 0; n < 4; ++n)
                acc[m][n] = __builtin_amdgcn_mfma_f32_16x16x32_fp8_fp8(af[m], bfr[n], acc[m][n], 0, 0, 0);
    }

    const float kexp = 2.8853901f;  // log2(e)/tau
#pragma unroll
    for (int m = 0; m < 8; ++m)
#pragma unroll
        for (int n = 0; n < 4; ++n)
#pragma unroll
            for (int r = 0; r < 4; ++r)
                acc[m][n][r] = exp2f(acc[m][n][r] * kexp);

    // rowsum partials: value (m,n,r): row = i*256 + wr*128 + m*16 + lk*4 + r (sum over wave's 64 cols)
    {
        float* dst = RPART + (size_t)(4 * j + wc) * NU + i * 256 + wr * 128;
#pragma unroll
        for (int m = 0; m < 8; ++m) {
            float rs[4];
#pragma unroll
            for (int r = 0; r < 4; ++r) {
                rs[r] = acc[m][0][r] + acc[m][1][r] + acc[m][2][r] + acc[m][3][r];
                rs[r] += __shfl_xor(rs[r], 1);
                rs[r] += __shfl_xor(rs[r], 2);
                rs[r] += __shfl_xor(rs[r], 4);
                rs[r] += __shfl_xor(rs[r], 8);
            }
            if (lr == 0) {
#pragma unroll
                for (int r = 0; r < 4; ++r) dst[m * 16 + lk * 4 + r] = rs[r];
            }
        }
    }
    // colsum partials (off-diag): col = j*256 + wc*64 + n*16 + lr (sum over wave's 128 rows)
    if (!diag) {
        float* dst = RPART + (size_t)(2 * i + wr) * NU + j * 256 + wc * 64;
#pragma unroll
        for (int n = 0; n < 4; ++n) {
            float cs = 0.f;
#pragma unroll
            for (int m = 0; m < 8; ++m)
#pragma unroll
                for (int r = 0; r < 4; ++r) cs += acc[m][n][r];
            cs += __shfl_xor(cs, 16);
            cs += __shfl_xor(cs, 32);
            if (lk == 0) dst[n * 16 + lr] = cs;
        }
    }
}

// ---------- reduce partials: S[r] = sum_s RPART[s][r] ----------
__global__ __launch_bounds__(256) void reduce_part_kernel(const float* __restrict__ RPART,
                                                          float* __restrict__ S) {
    const int r = blockIdx.x * 256 + threadIdx.x;
    float s = 0.f;
#pragma unroll 8
    for (int p = 0; p < NSUB; ++p) s += RPART[(size_t)p * NU + r];
    S[r] = s;
}

// ---------- loss ----------
__global__ __launch_bounds__(128) void loss_partial_kernel(const float* __restrict__ S,
                                                           const float* __restrict__ dvec,
                                                           float* __restrict__ partial) {
    int i = blockIdx.x * 128 + threadIdx.x;
    const float e2 = 7.389056099f;  // exp(1/tau)
    float d = dvec[i];
    float l1 = logf(S[i] - e2) - d;
    float l2 = logf(S[NR + i] - e2) - d;
    float v = 0.5f * (l1 + l2);
#pragma unroll
    for (int m = 32; m; m >>= 1) v += __shfl_xor(v, m);
    __shared__ float wsum[2];
    if ((threadIdx.x & 63) == 0) wsum[threadIdx.x >> 6] = v;
    __syncthreads();
    if (threadIdx.x == 0) partial[blockIdx.x] = wsum[0] + wsum[1];
}

__global__ __launch_bounds__(128) void loss_final_kernel(const float* __restrict__ partial,
                                                         float* __restrict__ out, int nb) {
    float s = 0.f;
    for (int i = threadIdx.x; i < nb; i += 128) s += partial[i];
#pragma unroll
    for (int m = 32; m; m >>= 1) s += __shfl_xor(s, m);
    __shared__ float wsum[2];
    if ((threadIdx.x & 63) == 0) wsum[threadIdx.x >> 6] = s;
    __syncthreads();
    if (threadIdx.x == 0) out[0] = (wsum[0] + wsum[1]) * (1.f / (float)NR);
}

extern "C" void kernel_launch(void* const* d_in, const int* in_sizes, int n_in,
                              void* d_out, int out_size, void* d_ws, size_t ws_size,
                              hipStream_t stream) {
    const float* z1 = (const float*)d_in[0];
    const float* z2 = (const float*)d_in[1];
    const float* W1 = (const float*)d_in[2];
    const float* b1 = (const float*)d_in[3];
    const float* W2 = (const float*)d_in[4];
    const float* b2 = (const float*)d_in[5];

    char* ws = (char*)d_ws;
    size_t off = 0;
    auto alloc = [&](size_t bytes) {
        void* p = ws + off;
        off += (bytes + 255) & ~(size_t)255;
        return p;
    };
    const size_t NH2 = (size_t)NR * HD * 2;  // bf16 matrix bytes (6.29 MB)
    unsigned short* zb1 = (unsigned short*)alloc(NH2);
    unsigned short* zb2 = (unsigned short*)alloc(NH2);
    unsigned short* W1t = (unsigned short*)alloc(HD * HD * 2);
    unsigned short* W2t = (unsigned short*)alloc(HD * HD * 2);
    unsigned short* t1 = (unsigned short*)alloc(NH2);
    unsigned short* t2 = (unsigned short*)alloc(NH2);
    float* h1 = (float*)alloc((size_t)NR * HD * 4);
    float* h2 = (float*)alloc((size_t)NR * HD * 4);
    unsigned char* nU = (unsigned char*)alloc((size_t)NU * HD);   // fp8
    float* S = (float*)alloc((size_t)NU * 4);
    float* dvec = (float*)alloc(NR * 4);
    float* partial = (float*)alloc(96 * 4);
    // RPART aliases the dead zb/W/t chain + most of h1 (all consumed before memset below).
    float* RPART = (float*)ws;  // 384*24576*4 = 37,748,736 B < h2 offset (38,010,880)

    const int n4 = NR * HD / 4;
    cast4_kernel<<<(n4 + 255) / 256, 256, 0, stream>>>(z1, zb1, n4);
    cast4_kernel<<<(n4 + 255) / 256, 256, 0, stream>>>(z2, zb2, n4);
    transpose_cast_kernel<<<HD, 256, 0, stream>>>(W1, W1t);
    transpose_cast_kernel<<<HD, 256, 0, stream>>>(W2, W2t);

    proj_kernel<1><<<NR / 64, 256, 0, stream>>>(zb1, W1t, b1, t1);
    proj_kernel<1><<<NR / 64, 256, 0, stream>>>(zb2, W1t, b1, t2);
    proj_kernel<0><<<NR / 64, 256, 0, stream>>>(t1, W2t, b2, h1);
    proj_kernel<0><<<NR / 64, 256, 0, stream>>>(t2, W2t, b2, h2);

    norm_diag_kernel<<<NR / 4, 256, 0, stream>>>(h1, h2, nU, nU + (size_t)NR * HD, dvec);

    hipMemsetAsync(RPART, 0, (size_t)NSUB * NU * 4, stream);

    gram_kernel<<<NBLK, 512, 0, stream>>>(nU, RPART);

    reduce_part_kernel<<<NU / 256, 256, 0, stream>>>(RPART, S);

    loss_partial_kernel<<<NR / 128, 128, 0, stream>>>(S, dvec, partial);
    loss_final_kernel<<<1, 128, 0, stream>>>(partial, (float*)d_out, NR / 128);
}

// Round 6
// 326.899 us; speedup vs baseline: 1.4321x; 1.0117x over previous
//
#include <hip/hip_runtime.h>
#include <hip/hip_bf16.h>

typedef __attribute__((ext_vector_type(4))) float f32x4;
typedef __attribute__((ext_vector_type(8))) short bf16x8;

#define NR 12288
#define HD 256
#define TAU 0.5f
#define NU 24576              // unified rows (n1;n2)
#define NP 96                 // 256-row panels of unified matrix
#define NSUB 384              // partial-sum slots
#define NBLK (NP * (NP + 1) / 2)   // 4656 = 8 * 582

__device__ __forceinline__ unsigned short f2bf(float f) {
    unsigned int x = __builtin_bit_cast(unsigned int, f);
    x += 0x7fffu + ((x >> 16) & 1u);
    return (unsigned short)(x >> 16);
}

// manual OCP e4m3fn cast, RNE in normal range, step-round in denormal range
__device__ __forceinline__ unsigned char f2e4m3(float f) {
    unsigned int u = __builtin_bit_cast(unsigned int, f);
    unsigned int s = (u >> 24) & 0x80u;
    float af = fabsf(f);
    if (af >= 464.f) return (unsigned char)(s | 0x7Eu);      // saturate to 448
    if (af < 0.015625f) {                                    // denormal: step 2^-9
        unsigned int q = (unsigned int)(af * 512.f + 0.5f);
        return (unsigned char)(s | q);
    }
    int e = (int)((u >> 23) & 0xffu) - 127;
    unsigned int mant = u & 0x7fffffu;
    unsigned int val = (unsigned int)((e + 7) << 3) | (mant >> 20);
    unsigned int rem = mant & 0xfffffu;
    val += (rem > 0x80000u) || (rem == 0x80000u && (val & 1u));
    return (unsigned char)(s | val);
}

// ---------- cast f32 -> bf16 (4 elems/thread) ----------
__global__ __launch_bounds__(256) void cast4_kernel(const float* __restrict__ src,
                                                    unsigned short* __restrict__ dst, int n4) {
    int i = blockIdx.x * 256 + threadIdx.x;
    if (i >= n4) return;
    float4 v = ((const float4*)src)[i];
    ushort4 u;
    u.x = f2bf(v.x); u.y = f2bf(v.y); u.z = f2bf(v.z); u.w = f2bf(v.w);
    ((ushort4*)dst)[i] = u;
}

// ---------- W[k][n] f32 -> Wt[n][k] bf16 ----------
__global__ __launch_bounds__(256) void transpose_cast_kernel(const float* __restrict__ W,
                                                             unsigned short* __restrict__ Wt) {
    int n = blockIdx.x;
    int k = threadIdx.x;
    Wt[n * HD + k] = f2bf(W[k * HD + n]);
}

// ---------- projection GEMM: C[M,256] = A[M,256] @ Bt[256,256]^T (+bias, opt elu) ----------
template <int ELU>
__global__ __launch_bounds__(256) void proj_kernel(const unsigned short* __restrict__ A,
                                                   const unsigned short* __restrict__ Bt,
                                                   const float* __restrict__ bias,
                                                   void* __restrict__ Cout) {
    const int lane = threadIdx.x & 63;
    const int wave = threadIdx.x >> 6;
    const int row0 = blockIdx.x * 64;
    const int col0 = wave * 64;
    const int lr = lane & 15, lk = lane >> 4;

    f32x4 acc[4][4] = {};
    const unsigned short* Ab = A + (size_t)(row0 + lr) * HD + lk * 8;
    const unsigned short* Bb = Bt + (size_t)(col0 + lr) * HD + lk * 8;
#pragma unroll
    for (int k0 = 0; k0 < HD; k0 += 32) {
        bf16x8 af[4], bfr[4];
#pragma unroll
        for (int m = 0; m < 4; ++m) af[m] = *(const bf16x8*)(Ab + m * 16 * HD + k0);
#pragma unroll
        for (int n = 0; n < 4; ++n) bfr[n] = *(const bf16x8*)(Bb + n * 16 * HD + k0);
#pragma unroll
        for (int m = 0; m < 4; ++m)
#pragma unroll
            for (int n = 0; n < 4; ++n)
                acc[m][n] = __builtin_amdgcn_mfma_f32_16x16x32_bf16(af[m], bfr[n], acc[m][n], 0, 0, 0);
    }
#pragma unroll
    for (int m = 0; m < 4; ++m) {
#pragma unroll
        for (int n = 0; n < 4; ++n) {
            int col = col0 + n * 16 + lr;
            float b = bias[col];
#pragma unroll
            for (int r = 0; r < 4; ++r) {
                int row = row0 + m * 16 + lk * 4 + r;
                float v = acc[m][n][r] + b;
                if (ELU) {
                    v = v > 0.f ? v : expm1f(v);
                    ((unsigned short*)Cout)[(size_t)row * HD + col] = f2bf(v);
                } else {
                    ((float*)Cout)[(size_t)row * HD + col] = v;
                }
            }
        }
    }
}

// ---------- normalize rows (fp32) -> fp8 e4m3 into unified buffer, plus fp32 diag dot / tau ----------
// nU8 layout: within each row, the two 8B halves of every 16B chunk are SWAPPED for rows
// with bit3 set (store addr ^= ((row>>3)&1)<<3). This pre-bakes the LDS bank half-swap so
// global_load_lds (verbatim 16B copy) lands data where the conflict-free read expects it.
__global__ __launch_bounds__(256) void norm_diag_kernel(const float* __restrict__ h1,
                                                        const float* __restrict__ h2,
                                                        unsigned char* __restrict__ n1,
                                                        unsigned char* __restrict__ n2,
                                                        float* __restrict__ dvec) {
    const int lane = threadIdx.x & 63;
    const int wave = threadIdx.x >> 6;
    const int row = blockIdx.x * 4 + wave;
    const float4 a = *(const float4*)(h1 + (size_t)row * HD + lane * 4);
    const float4 b = *(const float4*)(h2 + (size_t)row * HD + lane * 4);
    float sa = a.x * a.x + a.y * a.y + a.z * a.z + a.w * a.w;
    float sb = b.x * b.x + b.y * b.y + b.z * b.z + b.w * b.w;
    float sab = a.x * b.x + a.y * b.y + a.z * b.z + a.w * b.w;
#pragma unroll
    for (int m = 32; m; m >>= 1) {
        sa += __shfl_xor(sa, m);
        sb += __shfl_xor(sb, m);
        sab += __shfl_xor(sab, m);
    }
    float na = sqrtf(sa); na = na > 1e-12f ? na : 1e-12f;
    float nb = sqrtf(sb); nb = nb > 1e-12f ? nb : 1e-12f;
    float ia = 1.f / na, ib = 1.f / nb;
    uchar4 q1, q2;
    q1.x = f2e4m3(a.x * ia); q1.y = f2e4m3(a.y * ia); q1.z = f2e4m3(a.z * ia); q1.w = f2e4m3(a.w * ia);
    q2.x = f2e4m3(b.x * ib); q2.y = f2e4m3(b.y * ib); q2.z = f2e4m3(b.z * ib); q2.w = f2e4m3(b.w * ib);
    const int sw = ((row >> 3) & 1) << 3;                    // half-swap by row bit3
    *(uchar4*)(n1 + (size_t)row * HD + ((lane * 4) ^ sw)) = q1;
    *(uchar4*)(n2 + (size_t)row * HD + ((lane * 4) ^ sw)) = q2;
    if (lane == 0) dvec[row] = sab * ia * ib * (1.f / TAU);
}

// ---------- unified symmetric Gram (fp8): upper-tri 256x256 tiles of exp(M@M^T/tau) ----------
// Both full K=256 panels resident in LDS (64 KiB each): ONE staging burst + ONE barrier,
// then a barrier-free MFMA loop. Conflict-free b64 reads: 16B-chunk XOR swizzle
// (chunk ^= row&15) + 8B half-swap (half = (lk&1) ^ (row>>3 & 1)) so each 16-lane
// quarter (fixed lk) maps bijectively onto all 32 banks. Both sides per rule #21:
// chunk swizzle via pre-swizzled global source; half-swap pre-baked in nU8 layout.
__global__ __launch_bounds__(512, 2) void gram_kernel(const unsigned char* __restrict__ nU8,
                                                      float* __restrict__ RPART) {
    __shared__ __align__(16) unsigned char lA[256 * 256];  // 64KB
    __shared__ __align__(16) unsigned char lB[256 * 256];  // 64KB

    // XCD-aware swizzle (bijective: 4656 = 8*582), then tri decode (i<=j) over NP=96
    const int bid = blockIdx.x;
    const int t0 = (bid & 7) * (NBLK / 8) + (bid >> 3);
    int i = (int)((193.f - sqrtf((float)(193 * 193 - 8 * t0))) * 0.5f);
    if (i < 0) i = 0;
    if (i > NP - 1) i = NP - 1;
    while (i > 0 && i * NP - i * (i - 1) / 2 > t0) --i;
    while ((i + 1) * NP - (i + 1) * i / 2 <= t0) ++i;
    const int j = i + (t0 - (i * NP - i * (i - 1) / 2));
    const bool diag = (i == j);

    const unsigned char* X = nU8 + (size_t)i * 256 * HD;
    const unsigned char* Y = nU8 + (size_t)j * 256 * HD;

    const int t = threadIdx.x;
    const int lane = t & 63;
    const int wave = t >> 6;
    const int wr = wave >> 2, wc = wave & 3;      // 2M x 4N wave grid; wave tile 128x64
    const int lr = lane & 15, lk = lane >> 4;

    // ---- stage both panels: per thread 8 chunks of 16B per operand ----
    {
        const int rbase = t >> 4;                              // 0..31
        const int schunk = (t & 15) ^ (rbase & 15);            // pre-swizzled source slot
        const unsigned char* gx = X + rbase * 256 + schunk * 16;
        const unsigned char* gy = Y + rbase * 256 + schunk * 16;
#pragma unroll
        for (int c = 0; c < 8; ++c) {
            __builtin_amdgcn_global_load_lds(
                (const __attribute__((address_space(1))) unsigned int*)(gx + c * 8192),
                (__attribute__((address_space(3))) unsigned int*)(&lA[c * 8192 + t * 16]),
                16, 0, 0);
        }
#pragma unroll
        for (int c = 0; c < 8; ++c) {
            __builtin_amdgcn_global_load_lds(
                (const __attribute__((address_space(1))) unsigned int*)(gy + c * 8192),
                (__attribute__((address_space(3))) unsigned int*)(&lB[c * 8192 + t * 16]),
                16, 0, 0);
        }
    }
    __syncthreads();   // vmcnt(0) + barrier; the ONLY barrier in this kernel

    // ---- barrier-free K-loop: 8 k-steps of K=32, fp8 MFMA ----
    f32x4 acc[8][4] = {};
    const int hswap = (lr >> 3) & 1;                           // row bit3 (uniform across frags)
    const unsigned char* sA = lA + (size_t)(wr * 128 + lr) * 256 + ((lk & 1) ^ hswap) * 8;
    const unsigned char* sB = lB + (size_t)(wc * 64 + lr) * 256 + ((lk & 1) ^ hswap) * 8;
#pragma unroll
    for (int ks = 0; ks < 8; ++ks) {
        const int chnk = ((2 * ks + (lk >> 1)) ^ lr) * 16;     // swizzled 16B chunk
        long af[8], bfr[4];
#pragma unroll
        for (int m = 0; m < 8; ++m)
            af[m] = *(const long*)(sA + m * 16 * 256 + chnk);
#pragma unroll
        for (int n = 0; n < 4; ++n)
            bfr[n] = *(const long*)(sB + n * 16 * 256 + chnk);
#pragma unroll
        for (int m = 0; m < 8; ++m)
#pragma unroll
            for (int n = 0; n < 4; ++n)
                acc[m][n] = __builtin_amdgcn_mfma_f32_16x16x32_fp8_fp8(af[m], bfr[n], acc[m][n], 0, 0, 0);
    }

    const float kexp = 2.8853901f;  // log2(e)/tau
#pragma unroll
    for (int m = 0; m < 8; ++m)
#pragma unroll
        for (int n = 0; n < 4; ++n)
#pragma unroll
            for (int r = 0; r < 4; ++r)
                acc[m][n][r] = exp2f(acc[m][n][r] * kexp);

    // rowsum partials: value (m,n,r): row = i*256 + wr*128 + m*16 + lk*4 + r (sum over wave's 64 cols)
    {
        float* dst = RPART + (size_t)(4 * j + wc) * NU + i * 256 + wr * 128;
#pragma unroll
        for (int m = 0; m < 8; ++m) {
            float rs[4];
#pragma unroll
            for (int r = 0; r < 4; ++r) {
                rs[r] = acc[m][0][r] + acc[m][1][r] + acc[m][2][r] + acc[m][3][r];
                rs[r] += __shfl_xor(rs[r], 1);
                rs[r] += __shfl_xor(rs[r], 2);
                rs[r] += __shfl_xor(rs[r], 4);
                rs[r] += __shfl_xor(rs[r], 8);
            }
            if (lr == 0) {
#pragma unroll
                for (int r = 0; r < 4; ++r) dst[m * 16 + lk * 4 + r] = rs[r];
            }
        }
    }
    // colsum partials (off-diag): col = j*256 + wc*64 + n*16 + lr (sum over wave's 128 rows)
    if (!diag) {
        float* dst = RPART + (size_t)(2 * i + wr) * NU + j * 256 + wc * 64;
#pragma unroll
        for (int n = 0; n < 4; ++n) {
            float cs = 0.f;
#pragma unroll
            for (int m = 0; m < 8; ++m)
#pragma unroll
                for (int r = 0; r < 4; ++r) cs += acc[m][n][r];
            cs += __shfl_xor(cs, 16);
            cs += __shfl_xor(cs, 32);
            if (lk == 0) dst[n * 16 + lr] = cs;
        }
    }
}

// ---------- reduce partials: S[r] = sum_s RPART[s][r] ----------
__global__ __launch_bounds__(256) void reduce_part_kernel(const float* __restrict__ RPART,
                                                          float* __restrict__ S) {
    const int r = blockIdx.x * 256 + threadIdx.x;
    float s = 0.f;
#pragma unroll 8
    for (int p = 0; p < NSUB; ++p) s += RPART[(size_t)p * NU + r];
    S[r] = s;
}

// ---------- loss ----------
__global__ __launch_bounds__(128) void loss_partial_kernel(const float* __restrict__ S,
                                                           const float* __restrict__ dvec,
                                                           float* __restrict__ partial) {
    int i = blockIdx.x * 128 + threadIdx.x;
    const float e2 = 7.389056099f;  // exp(1/tau)
    float d = dvec[i];
    float l1 = logf(S[i] - e2) - d;
    float l2 = logf(S[NR + i] - e2) - d;
    float v = 0.5f * (l1 + l2);
#pragma unroll
    for (int m = 32; m; m >>= 1) v += __shfl_xor(v, m);
    __shared__ float wsum[2];
    if ((threadIdx.x & 63) == 0) wsum[threadIdx.x >> 6] = v;
    __syncthreads();
    if (threadIdx.x == 0) partial[blockIdx.x] = wsum[0] + wsum[1];
}

__global__ __launch_bounds__(128) void loss_final_kernel(const float* __restrict__ partial,
                                                         float* __restrict__ out, int nb) {
    float s = 0.f;
    for (int i = threadIdx.x; i < nb; i += 128) s += partial[i];
#pragma unroll
    for (int m = 32; m; m >>= 1) s += __shfl_xor(s, m);
    __shared__ float wsum[2];
    if ((threadIdx.x & 63) == 0) wsum[threadIdx.x >> 6] = s;
    __syncthreads();
    if (threadIdx.x == 0) out[0] = (wsum[0] + wsum[1]) * (1.f / (float)NR);
}

extern "C" void kernel_launch(void* const* d_in, const int* in_sizes, int n_in,
                              void* d_out, int out_size, void* d_ws, size_t ws_size,
                              hipStream_t stream) {
    const float* z1 = (const float*)d_in[0];
    const float* z2 = (const float*)d_in[1];
    const float* W1 = (const float*)d_in[2];
    const float* b1 = (const float*)d_in[3];
    const float* W2 = (const float*)d_in[4];
    const float* b2 = (const float*)d_in[5];

    char* ws = (char*)d_ws;
    size_t off = 0;
    auto alloc = [&](size_t bytes) {
        void* p = ws + off;
        off += (bytes + 255) & ~(size_t)255;
        return p;
    };
    const size_t NH2 = (size_t)NR * HD * 2;  // bf16 matrix bytes (6.29 MB)
    unsigned short* zb1 = (unsigned short*)alloc(NH2);
    unsigned short* zb2 = (unsigned short*)alloc(NH2);
    unsigned short* W1t = (unsigned short*)alloc(HD * HD * 2);
    unsigned short* W2t = (unsigned short*)alloc(HD * HD * 2);
    unsigned short* t1 = (unsigned short*)alloc(NH2);
    unsigned short* t2 = (unsigned short*)alloc(NH2);
    float* h1 = (float*)alloc((size_t)NR * HD * 4);
    float* h2 = (float*)alloc((size_t)NR * HD * 4);
    unsigned char* nU = (unsigned char*)alloc((size_t)NU * HD);   // fp8
    float* S = (float*)alloc((size_t)NU * 4);
    float* dvec = (float*)alloc(NR * 4);
    float* partial = (float*)alloc(96 * 4);
    // RPART aliases the dead zb/W/t chain + most of h1 (all consumed before memset below).
    float* RPART = (float*)ws;  // 384*24576*4 = 37,748,736 B < h2 offset (38,010,880)

    const int n4 = NR * HD / 4;
    cast4_kernel<<<(n4 + 255) / 256, 256, 0, stream>>>(z1, zb1, n4);
    cast4_kernel<<<(n4 + 255) / 256, 256, 0, stream>>>(z2, zb2, n4);
    transpose_cast_kernel<<<HD, 256, 0, stream>>>(W1, W1t);
    transpose_cast_kernel<<<HD, 256, 0, stream>>>(W2, W2t);

    proj_kernel<1><<<NR / 64, 256, 0, stream>>>(zb1, W1t, b1, t1);
    proj_kernel<1><<<NR / 64, 256, 0, stream>>>(zb2, W1t, b1, t2);
    proj_kernel<0><<<NR / 64, 256, 0, stream>>>(t1, W2t, b2, h1);
    proj_kernel<0><<<NR / 64, 256, 0, stream>>>(t2, W2t, b2, h2);

    norm_diag_kernel<<<NR / 4, 256, 0, stream>>>(h1, h2, nU, nU + (size_t)NR * HD, dvec);

    hipMemsetAsync(RPART, 0, (size_t)NSUB * NU * 4, stream);

    gram_kernel<<<NBLK, 512, 0, stream>>>(nU, RPART);

    reduce_part_kernel<<<NU / 256, 256, 0, stream>>>(RPART, S);

    loss_partial_kernel<<<NR / 128, 128, 0, stream>>>(S, dvec, partial);
    loss_final_kernel<<<1, 128, 0, stream>>>(partial, (float*)d_out, NR / 128);
}

// Round 7
// 312.222 us; speedup vs baseline: 1.4994x; 1.0470x over previous
//
#include <hip/hip_runtime.h>
#include <hip/hip_bf16.h>

typedef __attribute__((ext_vector_type(4))) float f32x4;
typedef __attribute__((ext_vector_type(8))) short bf16x8;

#define NR 12288
#define HD 256
#define TAU 0.5f
#define NU 24576              // unified rows (n1;n2)
#define NTT 192               // 128-row tiles per dim of unified matrix
#define NSUB 384              // partial-sum slots
#define NBLK (NTT * (NTT + 1) / 2)   // 18528 = 8 * 2316

__device__ __forceinline__ unsigned short f2bf(float f) {
    unsigned int x = __builtin_bit_cast(unsigned int, f);
    x += 0x7fffu + ((x >> 16) & 1u);
    return (unsigned short)(x >> 16);
}

// manual OCP e4m3fn cast, RNE in normal range, step-round in denormal range
__device__ __forceinline__ unsigned char f2e4m3(float f) {
    unsigned int u = __builtin_bit_cast(unsigned int, f);
    unsigned int s = (u >> 24) & 0x80u;
    float af = fabsf(f);
    if (af >= 464.f) return (unsigned char)(s | 0x7Eu);      // saturate to 448
    if (af < 0.015625f) {                                    // denormal: step 2^-9
        unsigned int q = (unsigned int)(af * 512.f + 0.5f);
        return (unsigned char)(s | q);
    }
    int e = (int)((u >> 23) & 0xffu) - 127;
    unsigned int mant = u & 0x7fffffu;
    unsigned int val = (unsigned int)((e + 7) << 3) | (mant >> 20);
    unsigned int rem = mant & 0xfffffu;
    val += (rem > 0x80000u) || (rem == 0x80000u && (val & 1u));
    return (unsigned char)(s | val);
}

// ---------- cast f32 -> bf16 (4 elems/thread) ----------
__global__ __launch_bounds__(256) void cast4_kernel(const float* __restrict__ src,
                                                    unsigned short* __restrict__ dst, int n4) {
    int i = blockIdx.x * 256 + threadIdx.x;
    if (i >= n4) return;
    float4 v = ((const float4*)src)[i];
    ushort4 u;
    u.x = f2bf(v.x); u.y = f2bf(v.y); u.z = f2bf(v.z); u.w = f2bf(v.w);
    ((ushort4*)dst)[i] = u;
}

// ---------- W[k][n] f32 -> Wt[n][k] bf16 ----------
__global__ __launch_bounds__(256) void transpose_cast_kernel(const float* __restrict__ W,
                                                             unsigned short* __restrict__ Wt) {
    int n = blockIdx.x;
    int k = threadIdx.x;
    Wt[n * HD + k] = f2bf(W[k * HD + n]);
}

// ---------- projection GEMM: C[M,256] = A[M,256] @ Bt[256,256]^T (+bias, opt elu) ----------
template <int ELU>
__global__ __launch_bounds__(256) void proj_kernel(const unsigned short* __restrict__ A,
                                                   const unsigned short* __restrict__ Bt,
                                                   const float* __restrict__ bias,
                                                   void* __restrict__ Cout) {
    const int lane = threadIdx.x & 63;
    const int wave = threadIdx.x >> 6;
    const int row0 = blockIdx.x * 64;
    const int col0 = wave * 64;
    const int lr = lane & 15, lk = lane >> 4;

    f32x4 acc[4][4] = {};
    const unsigned short* Ab = A + (size_t)(row0 + lr) * HD + lk * 8;
    const unsigned short* Bb = Bt + (size_t)(col0 + lr) * HD + lk * 8;
#pragma unroll
    for (int k0 = 0; k0 < HD; k0 += 32) {
        bf16x8 af[4], bfr[4];
#pragma unroll
        for (int m = 0; m < 4; ++m) af[m] = *(const bf16x8*)(Ab + m * 16 * HD + k0);
#pragma unroll
        for (int n = 0; n < 4; ++n) bfr[n] = *(const bf16x8*)(Bb + n * 16 * HD + k0);
#pragma unroll
        for (int m = 0; m < 4; ++m)
#pragma unroll
            for (int n = 0; n < 4; ++n)
                acc[m][n] = __builtin_amdgcn_mfma_f32_16x16x32_bf16(af[m], bfr[n], acc[m][n], 0, 0, 0);
    }
#pragma unroll
    for (int m = 0; m < 4; ++m) {
#pragma unroll
        for (int n = 0; n < 4; ++n) {
            int col = col0 + n * 16 + lr;
            float b = bias[col];
#pragma unroll
            for (int r = 0; r < 4; ++r) {
                int row = row0 + m * 16 + lk * 4 + r;
                float v = acc[m][n][r] + b;
                if (ELU) {
                    v = v > 0.f ? v : expm1f(v);
                    ((unsigned short*)Cout)[(size_t)row * HD + col] = f2bf(v);
                } else {
                    ((float*)Cout)[(size_t)row * HD + col] = v;
                }
            }
        }
    }
}

// ---------- normalize rows (fp32) -> fp8 e4m3 into unified buffer, plus fp32 diag dot / tau ----------
// nU8 layout: the two 8B halves of every 16B chunk are SWAPPED for rows with bit3 set
// (store addr ^= ((row>>3)&1)<<3) — pre-bakes the LDS bank half-swap for conflict-free b64 reads.
__global__ __launch_bounds__(256) void norm_diag_kernel(const float* __restrict__ h1,
                                                        const float* __restrict__ h2,
                                                        unsigned char* __restrict__ n1,
                                                        unsigned char* __restrict__ n2,
                                                        float* __restrict__ dvec) {
    const int lane = threadIdx.x & 63;
    const int wave = threadIdx.x >> 6;
    const int row = blockIdx.x * 4 + wave;
    const float4 a = *(const float4*)(h1 + (size_t)row * HD + lane * 4);
    const float4 b = *(const float4*)(h2 + (size_t)row * HD + lane * 4);
    float sa = a.x * a.x + a.y * a.y + a.z * a.z + a.w * a.w;
    float sb = b.x * b.x + b.y * b.y + b.z * b.z + b.w * b.w;
    float sab = a.x * b.x + a.y * b.y + a.z * b.z + a.w * b.w;
#pragma unroll
    for (int m = 32; m; m >>= 1) {
        sa += __shfl_xor(sa, m);
        sb += __shfl_xor(sb, m);
        sab += __shfl_xor(sab, m);
    }
    float na = sqrtf(sa); na = na > 1e-12f ? na : 1e-12f;
    float nb = sqrtf(sb); nb = nb > 1e-12f ? nb : 1e-12f;
    float ia = 1.f / na, ib = 1.f / nb;
    uchar4 q1, q2;
    q1.x = f2e4m3(a.x * ia); q1.y = f2e4m3(a.y * ia); q1.z = f2e4m3(a.z * ia); q1.w = f2e4m3(a.w * ia);
    q2.x = f2e4m3(b.x * ib); q2.y = f2e4m3(b.y * ib); q2.z = f2e4m3(b.z * ib); q2.w = f2e4m3(b.w * ib);
    const int sw = ((row >> 3) & 1) << 3;                    // half-swap by row bit3
    *(uchar4*)(n1 + (size_t)row * HD + ((lane * 4) ^ sw)) = q1;
    *(uchar4*)(n2 + (size_t)row * HD + ((lane * 4) ^ sw)) = q2;
    if (lane == 0) dvec[row] = sab * ia * ib * (1.f / TAU);
}

// ---------- unified symmetric Gram (fp8): upper-tri 128x128 tiles of exp(M@M^T/tau) ----------
// 64 KiB LDS/block -> 2 blocks/CU: independent co-resident blocks overlap stage/epilogue
// of one with the MFMA loop of the other (no shared barriers). Both full-K panels LDS-resident,
// single __syncthreads, barrier-free K-loop. Conflict-free b64 reads: 16B-chunk XOR swizzle
// (chunk ^= row&15, pre-swizzled global source) + 8B half-swap (pre-baked in nU8 layout).
// Partial slots: rowsum -> RPART[2j+wc] at panel-i rows; colsum (i<j) -> RPART[2i+wr] at
// panel-j rows. Panel p receives rowsum slots [2p,384) and colsum slots [0,2p): disjoint.
__global__ __launch_bounds__(256, 2) void gram_kernel(const unsigned char* __restrict__ nU8,
                                                      float* __restrict__ RPART) {
    __shared__ __align__(16) unsigned char lA[128 * 256];  // 32KB
    __shared__ __align__(16) unsigned char lB[128 * 256];  // 32KB

    // XCD-aware swizzle (bijective: 18528 = 8*2316), then tri decode (i<=j) over NTT=192
    const int bid = blockIdx.x;
    const int t0 = (bid & 7) * (NBLK / 8) + (bid >> 3);
    int i = (int)((385.f - sqrtf((float)(385 * 385 - 8 * t0))) * 0.5f);
    if (i < 0) i = 0;
    if (i > NTT - 1) i = NTT - 1;
    while (i > 0 && i * NTT - i * (i - 1) / 2 > t0) --i;
    while ((i + 1) * NTT - (i + 1) * i / 2 <= t0) ++i;
    const int j = i + (t0 - (i * NTT - i * (i - 1) / 2));
    const bool diag = (i == j);

    const unsigned char* X = nU8 + (size_t)i * 128 * HD;
    const unsigned char* Y = nU8 + (size_t)j * 128 * HD;

    const int t = threadIdx.x;
    const int lane = t & 63;
    const int wave = t >> 6;
    const int wr = wave >> 1, wc = wave & 1;      // 2x2 wave grid; wave tile 64x64
    const int lr = lane & 15, lk = lane >> 4;

    // ---- stage panel(s): per thread 8 chunks of 16B per operand ----
    {
        const int rbase = t >> 4;                              // 0..15
        const int schunk = (t & 15) ^ rbase;                   // pre-swizzled source slot
        const unsigned char* gx = X + rbase * 256 + schunk * 16;
        const unsigned char* gy = Y + rbase * 256 + schunk * 16;
#pragma unroll
        for (int c = 0; c < 8; ++c) {                          // rows c*16 + rbase
            __builtin_amdgcn_global_load_lds(
                (const __attribute__((address_space(1))) unsigned int*)(gx + c * 4096),
                (__attribute__((address_space(3))) unsigned int*)(&lA[c * 4096 + t * 16]),
                16, 0, 0);
        }
        if (!diag) {
#pragma unroll
            for (int c = 0; c < 8; ++c) {
                __builtin_amdgcn_global_load_lds(
                    (const __attribute__((address_space(1))) unsigned int*)(gy + c * 4096),
                    (__attribute__((address_space(3))) unsigned int*)(&lB[c * 4096 + t * 16]),
                    16, 0, 0);
            }
        }
    }
    __syncthreads();   // the ONLY barrier in this kernel

    // ---- barrier-free K-loop: 8 k-steps of K=32, fp8 MFMA ----
    f32x4 acc[4][4] = {};
    const int hswap = (lr >> 3) & 1;                           // row bit3 (uniform across frags)
    const unsigned char* sA = lA + (size_t)(wr * 64 + lr) * 256 + ((lk & 1) ^ hswap) * 8;
    const unsigned char* sBb = (diag ? lA : lB);
    const unsigned char* sB = sBb + (size_t)(wc * 64 + lr) * 256 + ((lk & 1) ^ hswap) * 8;
#pragma unroll
    for (int ks = 0; ks < 8; ++ks) {
        const int chnk = ((2 * ks + (lk >> 1)) ^ lr) * 16;     // swizzled 16B chunk
        long af[4], bfr[4];
#pragma unroll
        for (int m = 0; m < 4; ++m)
            af[m] = *(const long*)(sA + m * 16 * 256 + chnk);
#pragma unroll
        for (int n = 0; n < 4; ++n)
            bfr[n] = *(const long*)(sB + n * 16 * 256 + chnk);
#pragma unroll
        for (int m = 0; m < 4; ++m)
#pragma unroll
            for (int n = 0; n < 4; ++n)
                acc[m][n] = __builtin_amdgcn_mfma_f32_16x16x32_fp8_fp8(af[m], bfr[n], acc[m][n], 0, 0, 0);
    }

    const float kexp = 2.8853901f;  // log2(e)/tau
#pragma unroll
    for (int m = 0; m < 4; ++m)
#pragma unroll
        for (int n = 0; n < 4; ++n)
#pragma unroll
            for (int r = 0; r < 4; ++r)
                acc[m][n][r] = exp2f(acc[m][n][r] * kexp);

    // rowsum partials: value (m,n,r): row = i*128 + wr*64 + m*16 + lk*4 + r (sum over wave's 64 cols)
    {
        float* dst = RPART + (size_t)(2 * j + wc) * NU + i * 128 + wr * 64;
#pragma unroll
        for (int m = 0; m < 4; ++m) {
            float rs[4];
#pragma unroll
            for (int r = 0; r < 4; ++r) {
                rs[r] = acc[m][0][r] + acc[m][1][r] + acc[m][2][r] + acc[m][3][r];
                rs[r] += __shfl_xor(rs[r], 1);
                rs[r] += __shfl_xor(rs[r], 2);
                rs[r] += __shfl_xor(rs[r], 4);
                rs[r] += __shfl_xor(rs[r], 8);
            }
            if (lr == 0) {
#pragma unroll
                for (int r = 0; r < 4; ++r) dst[m * 16 + lk * 4 + r] = rs[r];
            }
        }
    }
    // colsum partials (off-diag): col = j*128 + wc*64 + n*16 + lr (sum over wave's 64 rows)
    if (!diag) {
        float* dst = RPART + (size_t)(2 * i + wr) * NU + j * 128 + wc * 64;
#pragma unroll
        for (int n = 0; n < 4; ++n) {
            float cs = 0.f;
#pragma unroll
            for (int m = 0; m < 4; ++m)
#pragma unroll
                for (int r = 0; r < 4; ++r) cs += acc[m][n][r];
            cs += __shfl_xor(cs, 16);
            cs += __shfl_xor(cs, 32);
            if (lk == 0) dst[n * 16 + lr] = cs;
        }
    }
}

// ---------- reduce partials: S[r] = sum_s RPART[s][r] ----------
__global__ __launch_bounds__(256) void reduce_part_kernel(const float* __restrict__ RPART,
                                                          float* __restrict__ S) {
    const int r = blockIdx.x * 256 + threadIdx.x;
    float s = 0.f;
#pragma unroll 8
    for (int p = 0; p < NSUB; ++p) s += RPART[(size_t)p * NU + r];
    S[r] = s;
}

// ---------- loss ----------
__global__ __launch_bounds__(128) void loss_partial_kernel(const float* __restrict__ S,
                                                           const float* __restrict__ dvec,
                                                           float* __restrict__ partial) {
    int i = blockIdx.x * 128 + threadIdx.x;
    const float e2 = 7.389056099f;  // exp(1/tau)
    float d = dvec[i];
    float l1 = logf(S[i] - e2) - d;
    float l2 = logf(S[NR + i] - e2) - d;
    float v = 0.5f * (l1 + l2);
#pragma unroll
    for (int m = 32; m; m >>= 1) v += __shfl_xor(v, m);
    __shared__ float wsum[2];
    if ((threadIdx.x & 63) == 0) wsum[threadIdx.x >> 6] = v;
    __syncthreads();
    if (threadIdx.x == 0) partial[blockIdx.x] = wsum[0] + wsum[1];
}

__global__ __launch_bounds__(128) void loss_final_kernel(const float* __restrict__ partial,
                                                         float* __restrict__ out, int nb) {
    float s = 0.f;
    for (int i = threadIdx.x; i < nb; i += 128) s += partial[i];
#pragma unroll
    for (int m = 32; m; m >>= 1) s += __shfl_xor(s, m);
    __shared__ float wsum[2];
    if ((threadIdx.x & 63) == 0) wsum[threadIdx.x >> 6] = s;
    __syncthreads();
    if (threadIdx.x == 0) out[0] = (wsum[0] + wsum[1]) * (1.f / (float)NR);
}

extern "C" void kernel_launch(void* const* d_in, const int* in_sizes, int n_in,
                              void* d_out, int out_size, void* d_ws, size_t ws_size,
                              hipStream_t stream) {
    const float* z1 = (const float*)d_in[0];
    const float* z2 = (const float*)d_in[1];
    const float* W1 = (const float*)d_in[2];
    const float* b1 = (const float*)d_in[3];
    const float* W2 = (const float*)d_in[4];
    const float* b2 = (const float*)d_in[5];

    char* ws = (char*)d_ws;
    size_t off = 0;
    auto alloc = [&](size_t bytes) {
        void* p = ws + off;
        off += (bytes + 255) & ~(size_t)255;
        return p;
    };
    const size_t NH2 = (size_t)NR * HD * 2;  // bf16 matrix bytes (6.29 MB)
    unsigned short* zb1 = (unsigned short*)alloc(NH2);
    unsigned short* zb2 = (unsigned short*)alloc(NH2);
    unsigned short* W1t = (unsigned short*)alloc(HD * HD * 2);
    unsigned short* W2t = (unsigned short*)alloc(HD * HD * 2);
    unsigned short* t1 = (unsigned short*)alloc(NH2);
    unsigned short* t2 = (unsigned short*)alloc(NH2);
    float* h1 = (float*)alloc((size_t)NR * HD * 4);
    float* h2 = (float*)alloc((size_t)NR * HD * 4);
    unsigned char* nU = (unsigned char*)alloc((size_t)NU * HD);   // fp8
    float* S = (float*)alloc((size_t)NU * 4);
    float* dvec = (float*)alloc(NR * 4);
    float* partial = (float*)alloc(96 * 4);
    // RPART aliases the dead zb/W/t chain + most of h1 (all consumed before memset below).
    float* RPART = (float*)ws;  // 384*24576*4 = 37,748,736 B < h2 offset (38,010,880)

    const int n4 = NR * HD / 4;
    cast4_kernel<<<(n4 + 255) / 256, 256, 0, stream>>>(z1, zb1, n4);
    cast4_kernel<<<(n4 + 255) / 256, 256, 0, stream>>>(z2, zb2, n4);
    transpose_cast_kernel<<<HD, 256, 0, stream>>>(W1, W1t);
    transpose_cast_kernel<<<HD, 256, 0, stream>>>(W2, W2t);

    proj_kernel<1><<<NR / 64, 256, 0, stream>>>(zb1, W1t, b1, t1);
    proj_kernel<1><<<NR / 64, 256, 0, stream>>>(zb2, W1t, b1, t2);
    proj_kernel<0><<<NR / 64, 256, 0, stream>>>(t1, W2t, b2, h1);
    proj_kernel<0><<<NR / 64, 256, 0, stream>>>(t2, W2t, b2, h2);

    norm_diag_kernel<<<NR / 4, 256, 0, stream>>>(h1, h2, nU, nU + (size_t)NR * HD, dvec);

    hipMemsetAsync(RPART, 0, (size_t)NSUB * NU * 4, stream);

    gram_kernel<<<NBLK, 256, 0, stream>>>(nU, RPART);

    reduce_part_kernel<<<NU / 256, 256, 0, stream>>>(RPART, S);

    loss_partial_kernel<<<NR / 128, 128, 0, stream>>>(S, dvec, partial);
    loss_final_kernel<<<1, 128, 0, stream>>>(partial, (float*)d_out, NR / 128);
}